// Round 16
// baseline (143.910 us; speedup 1.0000x reference)
//
#include <hip/hip_runtime.h>

typedef float f32x4 __attribute__((ext_vector_type(4)));
typedef short bf16x8 __attribute__((ext_vector_type(8)));

__device__ __forceinline__ unsigned short f2bf(float f) {
  unsigned int u = __float_as_uint(f);
  u += 0x7FFFu + ((u >> 16) & 1u);  // RNE
  return (unsigned short)(u >> 16);
}
__device__ __forceinline__ float bflo(unsigned int u) {  // low bf16 -> f32
  return __uint_as_float(u << 16);
}
__device__ __forceinline__ float bfhi(unsigned int u) {  // high bf16 -> f32
  return __uint_as_float(u & 0xFFFF0000u);
}

// ---------------- build node -> compact id map ----------------
__global__ void k_build_map(const int* __restrict__ tri_nodes, int* __restrict__ map,
                            int* __restrict__ uniq, int* __restrict__ counter, int n) {
  int i = blockIdx.x * blockDim.x + threadIdx.x;
  if (i >= n) return;
  int node = tri_nodes[i];
  int old = atomicCAS(&map[node], -1, -2);
  if (old == -1) {
    int mid = atomicAdd(counter, 1);
    uniq[mid] = node;
    map[node] = mid;
  }
}

// ---------------- count needed edges per comb + (fused) X -> bf16 convert ----------
// The count pass is probe-latency-bound (VALUBusy ~2% at r12); the independent
// X16 streaming convert (1.6M uint4s == 1.6M threads, perfect slot match)
// overlaps its bandwidth under the map-probe stalls. total8 == 0 disables.
__global__ void k_count(const int* __restrict__ edst, const int* __restrict__ erel,
                        const int* __restrict__ map, int* __restrict__ cnt_c, int E,
                        const float* __restrict__ X, unsigned short* __restrict__ X16,
                        int total8) {
  int i = blockIdx.x * blockDim.x + threadIdx.x;
  if (i < total8) {  // fused cvt_x slice (independent work)
    const float4* s = (const float4*)(X + (size_t)i * 8);
    float4 v0 = s[0], v1 = s[1];
    uint4 p;
    p.x = (unsigned int)f2bf(v0.x) | ((unsigned int)f2bf(v0.y) << 16);
    p.y = (unsigned int)f2bf(v0.z) | ((unsigned int)f2bf(v0.w) << 16);
    p.z = (unsigned int)f2bf(v1.x) | ((unsigned int)f2bf(v1.y) << 16);
    p.w = (unsigned int)f2bf(v1.z) | ((unsigned int)f2bf(v1.w) << 16);
    ((uint4*)X16)[i] = p;
  }
  if (i >= E) return;
  int mid = map[edst[i]];
  if (mid >= 0) atomicAdd(&cnt_c[mid * 8 + erel[i]], 1);
}

// ---------------- hierarchical exclusive scan over M=262144 entries ----------------
__global__ __launch_bounds__(256) void k_scan_s1(const int* __restrict__ cnt_c,
                                                 int* __restrict__ bsum) {
  __shared__ int sh[256];
  int tid = threadIdx.x;
  int base = blockIdx.x * 1024 + tid * 4;
  int s = cnt_c[base] + cnt_c[base + 1] + cnt_c[base + 2] + cnt_c[base + 3];
  sh[tid] = s;
  __syncthreads();
  for (int o = 1; o < 256; o <<= 1) {
    int x = (tid >= o) ? sh[tid - o] : 0;
    __syncthreads();
    sh[tid] += x;
    __syncthreads();
  }
  if (tid == 255) bsum[blockIdx.x] = sh[255];
}
__global__ __launch_bounds__(256) void k_scan_s2(int* __restrict__ bsum,
                                                 int* __restrict__ seg_start, int M) {
  __shared__ int sh[256];
  int tid = threadIdx.x;
  int v = bsum[tid];
  sh[tid] = v;
  __syncthreads();
  for (int o = 1; o < 256; o <<= 1) {
    int x = (tid >= o) ? sh[tid - o] : 0;
    __syncthreads();
    sh[tid] += x;
    __syncthreads();
  }
  bsum[tid] = sh[tid] - v;  // exclusive
  if (tid == 255) seg_start[M] = sh[255];
}
__global__ __launch_bounds__(256) void k_scan_s3(const int* __restrict__ cnt_c,
                                                 const int* __restrict__ bsum,
                                                 int* __restrict__ seg_start,
                                                 int* __restrict__ seg_ofs) {
  __shared__ int sh[256];
  int tid = threadIdx.x;
  int base = blockIdx.x * 1024 + tid * 4;
  int c0 = cnt_c[base], c1 = cnt_c[base + 1], c2 = cnt_c[base + 2], c3 = cnt_c[base + 3];
  int s = c0 + c1 + c2 + c3;
  sh[tid] = s;
  __syncthreads();
  for (int o = 1; o < 256; o <<= 1) {
    int x = (tid >= o) ? sh[tid - o] : 0;
    __syncthreads();
    sh[tid] += x;
    __syncthreads();
  }
  int run = bsum[blockIdx.x] + sh[tid] - s;
  seg_start[base] = run; seg_ofs[base] = run; run += c0;
  seg_start[base + 1] = run; seg_ofs[base + 1] = run; run += c1;
  seg_start[base + 2] = run; seg_ofs[base + 2] = run; run += c2;
  seg_start[base + 3] = run; seg_ofs[base + 3] = run;
}

// ---------------- scatter needed edge srcs into comb-sorted order ----------------
__global__ void k_scatter(const int* __restrict__ esrc, const int* __restrict__ edst,
                          const int* __restrict__ erel, const int* __restrict__ map,
                          int* __restrict__ seg_ofs, int* __restrict__ s_src, int E) {
  int i = blockIdx.x * blockDim.x + threadIdx.x;
  if (i >= E) return;
  int mid = map[edst[i]];
  if (mid >= 0) {
    int comb = mid * 8 + erel[i];
    int pos = atomicAdd(&seg_ofs[comb], 1);
    s_src[pos] = esrc[i];
  }
}

// ---------------- W -> bf16 FRAGMENT-MAJOR: Wf[((r*16+ku)*128+col)*8+j] = W[r][ku*8+j][col]
__global__ void k_cvt_w(const float* __restrict__ W_rel, const float* __restrict__ W_self,
                        unsigned short* __restrict__ Wf) {
  int i = blockIdx.x * 256 + threadIdx.x;  // over 9*16384 bf16 elements
  if (i >= 9 * 16384) return;
  int j = i & 7;
  int tmp = i >> 3;
  int col = tmp & 127;
  int ku = (tmp >> 7) & 15;
  int r = tmp >> 11;
  int d = ku * 8 + j;
  float v = (r < 8) ? W_rel[r * 16384 + d * 128 + col] : W_self[d * 128 + col];
  Wf[i] = f2bf(v);
}

// ---------------- X -> bf16 standalone (only used if !bigws fp32 fallback) --------
__global__ void k_cvt_x(const float* __restrict__ X, unsigned short* __restrict__ X16,
                        int total8) {
  int i = blockIdx.x * 256 + threadIdx.x;
  if (i >= total8) return;
  const float4* s = (const float4*)(X + (size_t)i * 8);
  float4 v0 = s[0], v1 = s[1];
  uint4 p;
  p.x = (unsigned int)f2bf(v0.x) | ((unsigned int)f2bf(v0.y) << 16);
  p.y = (unsigned int)f2bf(v0.z) | ((unsigned int)f2bf(v0.w) << 16);
  p.z = (unsigned int)f2bf(v1.x) | ((unsigned int)f2bf(v1.y) << 16);
  p.w = (unsigned int)f2bf(v1.z) | ((unsigned int)f2bf(v1.w) << 16);
  ((uint4*)X16)[i] = p;
}

// ---------------- fused RGCN GEMM on matrix cores ----------------
// r15 structure + 4-deep explicit-load gather unroll in the LDS-index path:
// the barrier critical path per phase is the max-cnt thread (~6-8 edges);
// 4 loads in flight halve its serialized round-trips.
template <int XMODE>
__global__ __launch_bounds__(256) void k_fused(
    const float* __restrict__ X, const unsigned short* __restrict__ X16,
    const unsigned short* __restrict__ Wf, const float* __restrict__ bvec,
    const int* __restrict__ uniq, const int* __restrict__ counter,
    const int* __restrict__ seg_start, const int* __restrict__ s_src,
    float* __restrict__ Hacc) {
  __shared__ __align__(16) unsigned short a_lds[16 * 128];  // 4 KB, swizzled
  __shared__ int lds_src[768];                              // 3 KB index stage

  int nm = *counter;
  int mid0 = blockIdx.x * 16;
  if (mid0 >= nm) return;

  int t = threadIdx.x;
  int er = t >> 4, seg = t & 15;
  int lane = t & 63, l15 = lane & 15, lg = lane >> 4;
  int wc = t >> 6;
  int mid = mid0 + er;

  // stage this block's edge-index range (contiguous in comb-sorted order)
  int i0 = seg_start[mid0 * 8];
  int range = seg_start[mid0 * 8 + 128] - i0;
  for (int j = t; j < range && j < 768; j += 256) lds_src[j] = s_src[i0 + j];
  bool fits = (range <= 768);  // block-uniform

  f32x4 acc[2];
  {
    f32x4 z = {0.f, 0.f, 0.f, 0.f};
    acc[0] = z; acc[1] = z;
  }

  for (int r = 0; r < 9; ++r) {
    __syncthreads();  // orders staging (r=0) / prev MFMA before a_lds overwrite

    {  // stage A row er chunk seg (8 values)
      float aa[8];
#pragma unroll
      for (int q = 0; q < 8; ++q) aa[q] = 0.f;

      auto addrow = [&](int sidx) {
        if (XMODE == 0) {
          const float4* xr = (const float4*)(X + (size_t)sidx * 128) + seg * 2;
          float4 v0 = xr[0], v1 = xr[1];
          aa[0] += v0.x; aa[1] += v0.y; aa[2] += v0.z; aa[3] += v0.w;
          aa[4] += v1.x; aa[5] += v1.y; aa[6] += v1.z; aa[7] += v1.w;
        } else {
          uint4 u = *(const uint4*)(X16 + (size_t)sidx * 128 + seg * 8);
          aa[0] += bflo(u.x); aa[1] += bfhi(u.x);
          aa[2] += bflo(u.y); aa[3] += bfhi(u.y);
          aa[4] += bflo(u.z); aa[5] += bfhi(u.z);
          aa[6] += bflo(u.w); aa[7] += bfhi(u.w);
        }
      };

      if (r < 8) {
        int comb = mid * 8 + r;
        int s0 = seg_start[comb], s1 = seg_start[comb + 1];
        int cnt = s1 - s0;
        if (fits) {  // indices from LDS: chain = X16 load only
          int o = s0 - i0, oe = s1 - i0;
          if (XMODE == 1) {
            for (; o + 4 <= oe; o += 4) {  // 4 loads in flight before any add
              int ia = lds_src[o], ib = lds_src[o + 1];
              int ic = lds_src[o + 2], id = lds_src[o + 3];
              uint4 ua = *(const uint4*)(X16 + (size_t)ia * 128 + seg * 8);
              uint4 ub = *(const uint4*)(X16 + (size_t)ib * 128 + seg * 8);
              uint4 uc = *(const uint4*)(X16 + (size_t)ic * 128 + seg * 8);
              uint4 ud = *(const uint4*)(X16 + (size_t)id * 128 + seg * 8);
              aa[0] += bflo(ua.x) + bflo(ub.x) + bflo(uc.x) + bflo(ud.x);
              aa[1] += bfhi(ua.x) + bfhi(ub.x) + bfhi(uc.x) + bfhi(ud.x);
              aa[2] += bflo(ua.y) + bflo(ub.y) + bflo(uc.y) + bflo(ud.y);
              aa[3] += bfhi(ua.y) + bfhi(ub.y) + bfhi(uc.y) + bfhi(ud.y);
              aa[4] += bflo(ua.z) + bflo(ub.z) + bflo(uc.z) + bflo(ud.z);
              aa[5] += bfhi(ua.z) + bfhi(ub.z) + bfhi(uc.z) + bfhi(ud.z);
              aa[6] += bflo(ua.w) + bflo(ub.w) + bflo(uc.w) + bflo(ud.w);
              aa[7] += bfhi(ua.w) + bfhi(ub.w) + bfhi(uc.w) + bfhi(ud.w);
            }
          }
          for (; o + 2 <= oe; o += 2) {
            int ia = lds_src[o], ib = lds_src[o + 1];
            addrow(ia);
            addrow(ib);
          }
          if (o < oe) addrow(lds_src[o]);
        } else {  // rare fallback: original global path
          int e = s0;
          for (; e + 2 <= s1; e += 2) {
            int ia = s_src[e], ib = s_src[e + 1];
            addrow(ia);
            addrow(ib);
          }
          if (e < s1) addrow(s_src[e]);
        }
        if (cnt > 1) {
          float sc = 1.0f / (float)cnt;
#pragma unroll
          for (int q = 0; q < 8; ++q) aa[q] *= sc;
        }
      } else if (mid < nm) {
        addrow(uniq[mid]);
      }
      uint4 p;
      p.x = (unsigned int)f2bf(aa[0]) | ((unsigned int)f2bf(aa[1]) << 16);
      p.y = (unsigned int)f2bf(aa[2]) | ((unsigned int)f2bf(aa[3]) << 16);
      p.z = (unsigned int)f2bf(aa[4]) | ((unsigned int)f2bf(aa[5]) << 16);
      p.w = (unsigned int)f2bf(aa[6]) | ((unsigned int)f2bf(aa[7]) << 16);
      *(uint4*)&a_lds[(((er * 16 + seg) ^ (er & 7)) * 8)] = p;
    }
    __syncthreads();  // a_lds ready

    const unsigned short* wf = Wf + r * 16384;
#pragma unroll
    for (int kb = 0; kb < 4; ++kb) {
      int ku = kb * 4 + lg;
      bf16x8 af = *(const bf16x8*)&a_lds[((l15 * 16 + ku) ^ (l15 & 7)) * 8];
#pragma unroll
      for (int n = 0; n < 2; ++n) {
        int col = wc * 32 + n * 16 + l15;
        bf16x8 bfr = *(const bf16x8*)(wf + ((size_t)(ku * 128 + col)) * 8);
        acc[n] = __builtin_amdgcn_mfma_f32_16x16x32_bf16(af, bfr, acc[n], 0, 0, 0);
      }
    }
  }

  // epilogue: bias + relu, plain stores. C/D map: col=lane&15, row=(lane>>4)*4+reg
#pragma unroll
  for (int n = 0; n < 2; ++n) {
    int col = wc * 32 + n * 16 + l15;
    float bv = bvec[col];
#pragma unroll
    for (int q = 0; q < 4; ++q) {
      int row = mid0 + lg * 4 + q;
      float v = acc[n][q] + bv;
      Hacc[(size_t)row * 128 + col] = v > 0.f ? v : 0.f;
    }
  }
}

// ---------------- DistMult score: one wave per triple ----------------
__global__ void k_score(const float* __restrict__ H, const int* __restrict__ map,
                        const float* __restrict__ rel_emb, const int* __restrict__ tri_nodes,
                        const int* __restrict__ tri_rel, float* __restrict__ out, int B) {
  int w = (blockIdx.x * blockDim.x + threadIdx.x) >> 6;
  int lane = threadIdx.x & 63;
  if (w >= B) return;
  int s = map[tri_nodes[w * 2]];
  int o = map[tri_nodes[w * 2 + 1]];
  const float* hs = H + (size_t)s * 128;
  const float* ho = H + (size_t)o * 128;
  const float* rr = rel_emb + (size_t)tri_rel[w] * 128;
  float p = hs[lane] * ho[lane] * rr[lane] + hs[lane + 64] * ho[lane + 64] * rr[lane + 64];
#pragma unroll
  for (int ofs = 32; ofs > 0; ofs >>= 1) p += __shfl_down(p, ofs);
  if (lane == 0) out[w] = p;
}

extern "C" void kernel_launch(void* const* d_in, const int* in_sizes, int n_in,
                              void* d_out, int out_size, void* d_ws, size_t ws_size,
                              hipStream_t stream) {
  const float* X       = (const float*)d_in[0];
  const float* W_rel   = (const float*)d_in[1];
  const float* W_self  = (const float*)d_in[2];
  const float* bvec    = (const float*)d_in[3];
  const float* rel_emb = (const float*)d_in[4];
  const int* edge_src  = (const int*)d_in[5];
  const int* edge_dst  = (const int*)d_in[6];
  const int* edge_rel  = (const int*)d_in[7];
  const int* tri_nodes = (const int*)d_in[8];
  const int* tri_rel   = (const int*)d_in[9];

  int N  = in_sizes[0] / 128;   // 100000
  int E  = in_sizes[5];         // 1600000
  int nt = in_sizes[8];         // 2*B = 32768
  int B  = in_sizes[9];         // 16384
  int M  = nt * 8;              // 262144 combs

  char* ws = (char*)d_ws;
  int* map       = (int*)ws;                 // N
  int* counter   = map + N;                  // 1 (+pad 64)
  int* uniq      = counter + 64;             // nt
  int* cnt_c     = uniq + nt;                // M  (reused as Wf after scan_s3)
  int* seg_start = cnt_c + M;                // M+1 (+pad 64)
  int* seg_ofs   = seg_start + M + 64;       // M
  int* bsum      = seg_ofs + M;              // 256
  int* s_src     = bsum + 256;               // E
  float* Hacc    = (float*)(s_src + E);      // nt*128 floats
  unsigned short* Wf  = (unsigned short*)cnt_c;  // aliases dead cnt_c
  unsigned short* X16 = (unsigned short*)(Hacc + (size_t)nt * 128);  // N*128 bf16
  size_t need_big = ((char*)(X16 + (size_t)N * 128)) - ws;  // ~52.5 MB; ws ~268 MB
  bool bigws = ws_size >= need_big;

  hipMemsetAsync(map, 0xFF, (size_t)N * 4, stream);  // -1
  hipMemsetAsync(counter, 0, 64 * 4, stream);
  hipMemsetAsync(cnt_c, 0, (size_t)M * 4, stream);

  int eblocks = (E + 255) / 256;  // one thread per edge (== one per X16 uint4)
  k_build_map<<<(nt + 255) / 256, 256, 0, stream>>>(tri_nodes, map, uniq, counter, nt);
  k_count<<<eblocks, 256, 0, stream>>>(edge_dst, edge_rel, map, cnt_c, E,
                                       X, X16, bigws ? N * 16 : 0);
  k_scan_s1<<<256, 256, 0, stream>>>(cnt_c, bsum);
  k_scan_s2<<<1, 256, 0, stream>>>(bsum, seg_start, M);
  k_scan_s3<<<256, 256, 0, stream>>>(cnt_c, bsum, seg_start, seg_ofs);
  // cnt_c dead from here; overwrite with bf16 fragment-major weights
  k_cvt_w<<<(9 * 16384 + 255) / 256, 256, 0, stream>>>(W_rel, W_self, Wf);
  k_scatter<<<eblocks, 256, 0, stream>>>(edge_src, edge_dst, edge_rel, map, seg_ofs,
                                         s_src, E);
  if (bigws) {
    k_fused<1><<<nt / 16, 256, 0, stream>>>(X, X16, Wf, bvec, uniq, counter,
                                            seg_start, s_src, Hacc);
  } else {
    k_fused<0><<<nt / 16, 256, 0, stream>>>(X, X16, Wf, bvec, uniq, counter,
                                            seg_start, s_src, Hacc);
  }
  k_score<<<(B * 64 + 255) / 256, 256, 0, stream>>>(Hacc, map, rel_emb, tri_nodes,
                                                    tri_rel, (float*)d_out, B);
}

// Round 17
// 128.198 us; speedup vs baseline: 1.1226x; 1.1226x over previous
//
#include <hip/hip_runtime.h>

typedef float f32x4 __attribute__((ext_vector_type(4)));
typedef short bf16x8 __attribute__((ext_vector_type(8)));

__device__ __forceinline__ unsigned short f2bf(float f) {
  unsigned int u = __float_as_uint(f);
  u += 0x7FFFu + ((u >> 16) & 1u);  // RNE
  return (unsigned short)(u >> 16);
}
__device__ __forceinline__ float bflo(unsigned int u) {  // low bf16 -> f32
  return __uint_as_float(u << 16);
}
__device__ __forceinline__ float bfhi(unsigned int u) {  // high bf16 -> f32
  return __uint_as_float(u & 0xFFFF0000u);
}

// ---------------- build node -> compact id map ----------------
__global__ void k_build_map(const int* __restrict__ tri_nodes, int* __restrict__ map,
                            int* __restrict__ uniq, int* __restrict__ counter, int n) {
  int i = blockIdx.x * blockDim.x + threadIdx.x;
  if (i >= n) return;
  int node = tri_nodes[i];
  int old = atomicCAS(&map[node], -1, -2);
  if (old == -1) {
    int mid = atomicAdd(counter, 1);
    uniq[mid] = node;
    map[node] = mid;
  }
}

// ------- ONE E-pass: count + fused X->bf16 + wave-compacted (comb,src) pairs -------
// Wave-granular compaction: ballot rank within wave -> fixed slot c_pk[w*64+rank],
// wcount[w] = wave's valid count. NO barriers, NO returning global atomics
// (r13: per-thread hot atomic = 291us; r14: block-barrier coupling = 81us).
__global__ void k_count(const int* __restrict__ esrc, const int* __restrict__ edst,
                        const int* __restrict__ erel, const int* __restrict__ map,
                        int* __restrict__ cnt_c, int E,
                        const float* __restrict__ X, unsigned short* __restrict__ X16,
                        int total8, int2* __restrict__ c_pk, int* __restrict__ wcount) {
  int t = threadIdx.x;
  int i = blockIdx.x * 256 + t;
  if (i < total8) {  // fused cvt_x slice (independent streaming work)
    const float4* s = (const float4*)(X + (size_t)i * 8);
    float4 v0 = s[0], v1 = s[1];
    uint4 p;
    p.x = (unsigned int)f2bf(v0.x) | ((unsigned int)f2bf(v0.y) << 16);
    p.y = (unsigned int)f2bf(v0.z) | ((unsigned int)f2bf(v0.w) << 16);
    p.z = (unsigned int)f2bf(v1.x) | ((unsigned int)f2bf(v1.y) << 16);
    p.w = (unsigned int)f2bf(v1.z) | ((unsigned int)f2bf(v1.w) << 16);
    ((uint4*)X16)[i] = p;
  }
  bool valid = false;
  int comb = 0, src = 0;
  if (i < E) {
    int mid = map[edst[i]];
    if (mid >= 0) {
      valid = true;
      comb = mid * 8 + erel[i];
      src = esrc[i];
      atomicAdd(&cnt_c[comb], 1);  // 262K distinct addresses: low contention
    }
  }
  unsigned long long m = __ballot(valid);
  int lane = t & 63;
  int w = (blockIdx.x << 2) + (t >> 6);
  if (valid) {
    int rank = (int)__popcll(m & ((1ull << lane) - 1ull));
    c_pk[w * 64 + rank] = make_int2(comb, src);
  }
  if (lane == 0) wcount[w] = (int)__popcll(m);
}

// ---------------- hierarchical exclusive scan over M=262144 entries ----------------
__global__ __launch_bounds__(256) void k_scan_s1(const int* __restrict__ cnt_c,
                                                 int* __restrict__ bsum) {
  __shared__ int sh[256];
  int tid = threadIdx.x;
  int base = blockIdx.x * 1024 + tid * 4;
  int s = cnt_c[base] + cnt_c[base + 1] + cnt_c[base + 2] + cnt_c[base + 3];
  sh[tid] = s;
  __syncthreads();
  for (int o = 1; o < 256; o <<= 1) {
    int x = (tid >= o) ? sh[tid - o] : 0;
    __syncthreads();
    sh[tid] += x;
    __syncthreads();
  }
  if (tid == 255) bsum[blockIdx.x] = sh[255];
}
__global__ __launch_bounds__(256) void k_scan_s2(int* __restrict__ bsum,
                                                 int* __restrict__ seg_start, int M) {
  __shared__ int sh[256];
  int tid = threadIdx.x;
  int v = bsum[tid];
  sh[tid] = v;
  __syncthreads();
  for (int o = 1; o < 256; o <<= 1) {
    int x = (tid >= o) ? sh[tid - o] : 0;
    __syncthreads();
    sh[tid] += x;
    __syncthreads();
  }
  bsum[tid] = sh[tid] - v;  // exclusive
  if (tid == 255) seg_start[M] = sh[255];
}
__global__ __launch_bounds__(256) void k_scan_s3(const int* __restrict__ cnt_c,
                                                 const int* __restrict__ bsum,
                                                 int* __restrict__ seg_start,
                                                 int* __restrict__ seg_ofs) {
  __shared__ int sh[256];
  int tid = threadIdx.x;
  int base = blockIdx.x * 1024 + tid * 4;
  int c0 = cnt_c[base], c1 = cnt_c[base + 1], c2 = cnt_c[base + 2], c3 = cnt_c[base + 3];
  int s = c0 + c1 + c2 + c3;
  sh[tid] = s;
  __syncthreads();
  for (int o = 1; o < 256; o <<= 1) {
    int x = (tid >= o) ? sh[tid - o] : 0;
    __syncthreads();
    sh[tid] += x;
    __syncthreads();
  }
  int run = bsum[blockIdx.x] + sh[tid] - s;
  seg_start[base] = run; seg_ofs[base] = run; run += c0;
  seg_start[base + 1] = run; seg_ofs[base + 1] = run; run += c1;
  seg_start[base + 2] = run; seg_ofs[base + 2] = run; run += c2;
  seg_start[base + 3] = run; seg_ofs[base + 3] = run;
}

// ------- scatter from wave-compacted pairs (3.6 MB read vs 19.2 MB re-sweep) -------
__global__ void k_scatter2(const int2* __restrict__ c_pk, const int* __restrict__ wcount,
                           int* __restrict__ seg_ofs, int* __restrict__ s_src,
                           int nwaves) {
  int t = threadIdx.x;
  int w = blockIdx.x * 4 + (t >> 6);
  if (w >= nwaves) return;
  int lane = t & 63;
  if (lane < wcount[w]) {
    int2 p = c_pk[w * 64 + lane];
    int pos = atomicAdd(&seg_ofs[p.x], 1);
    s_src[pos] = p.y;
  }
}

// -------- fallback scatter (small-ws path only): original E-sweep --------
__global__ void k_scatter(const int* __restrict__ esrc, const int* __restrict__ edst,
                          const int* __restrict__ erel, const int* __restrict__ map,
                          int* __restrict__ seg_ofs, int* __restrict__ s_src, int E) {
  int i = blockIdx.x * blockDim.x + threadIdx.x;
  if (i >= E) return;
  int mid = map[edst[i]];
  if (mid >= 0) {
    int comb = mid * 8 + erel[i];
    int pos = atomicAdd(&seg_ofs[comb], 1);
    s_src[pos] = esrc[i];
  }
}

// ---------------- W -> bf16 FRAGMENT-MAJOR: Wf[((r*16+ku)*128+col)*8+j] = W[r][ku*8+j][col]
__global__ void k_cvt_w(const float* __restrict__ W_rel, const float* __restrict__ W_self,
                        unsigned short* __restrict__ Wf) {
  int i = blockIdx.x * 256 + threadIdx.x;  // over 9*16384 bf16 elements
  if (i >= 9 * 16384) return;
  int j = i & 7;
  int tmp = i >> 3;
  int col = tmp & 127;
  int ku = (tmp >> 7) & 15;
  int r = tmp >> 11;
  int d = ku * 8 + j;
  float v = (r < 8) ? W_rel[r * 16384 + d * 128 + col] : W_self[d * 128 + col];
  Wf[i] = f2bf(v);
}

// ---------------- fused RGCN GEMM on matrix cores (r15-proven version, verbatim) ---
template <int XMODE>
__global__ __launch_bounds__(256) void k_fused(
    const float* __restrict__ X, const unsigned short* __restrict__ X16,
    const unsigned short* __restrict__ Wf, const float* __restrict__ bvec,
    const int* __restrict__ uniq, const int* __restrict__ counter,
    const int* __restrict__ seg_start, const int* __restrict__ s_src,
    float* __restrict__ Hacc) {
  __shared__ __align__(16) unsigned short a_lds[16 * 128];  // 4 KB, swizzled
  __shared__ int lds_src[768];                              // 3 KB index stage

  int nm = *counter;
  int mid0 = blockIdx.x * 16;
  if (mid0 >= nm) return;

  int t = threadIdx.x;
  int er = t >> 4, seg = t & 15;
  int lane = t & 63, l15 = lane & 15, lg = lane >> 4;
  int wc = t >> 6;
  int mid = mid0 + er;

  // stage this block's edge-index range (contiguous in comb-sorted order)
  int i0 = seg_start[mid0 * 8];
  int range = seg_start[mid0 * 8 + 128] - i0;
  for (int j = t; j < range && j < 768; j += 256) lds_src[j] = s_src[i0 + j];
  bool fits = (range <= 768);  // block-uniform

  f32x4 acc[2];
  {
    f32x4 z = {0.f, 0.f, 0.f, 0.f};
    acc[0] = z; acc[1] = z;
  }

  for (int r = 0; r < 9; ++r) {
    __syncthreads();  // orders staging (r=0) / prev MFMA before a_lds overwrite

    {  // stage A row er chunk seg (8 values)
      float aa[8];
#pragma unroll
      for (int q = 0; q < 8; ++q) aa[q] = 0.f;

      auto addrow = [&](int sidx) {
        if (XMODE == 0) {
          const float4* xr = (const float4*)(X + (size_t)sidx * 128) + seg * 2;
          float4 v0 = xr[0], v1 = xr[1];
          aa[0] += v0.x; aa[1] += v0.y; aa[2] += v0.z; aa[3] += v0.w;
          aa[4] += v1.x; aa[5] += v1.y; aa[6] += v1.z; aa[7] += v1.w;
        } else {
          uint4 u = *(const uint4*)(X16 + (size_t)sidx * 128 + seg * 8);
          aa[0] += bflo(u.x); aa[1] += bfhi(u.x);
          aa[2] += bflo(u.y); aa[3] += bfhi(u.y);
          aa[4] += bflo(u.z); aa[5] += bfhi(u.z);
          aa[6] += bflo(u.w); aa[7] += bfhi(u.w);
        }
      };

      if (r < 8) {
        int comb = mid * 8 + r;
        int s0 = seg_start[comb], s1 = seg_start[comb + 1];
        int cnt = s1 - s0;
        if (fits) {  // indices from LDS: chain = X16 load only
          int o = s0 - i0, oe = s1 - i0;
          for (; o + 2 <= oe; o += 2) {
            int ia = lds_src[o], ib = lds_src[o + 1];
            addrow(ia);
            addrow(ib);
          }
          if (o < oe) addrow(lds_src[o]);
        } else {     // rare fallback: original global path
          int e = s0;
          for (; e + 2 <= s1; e += 2) {
            int ia = s_src[e], ib = s_src[e + 1];
            addrow(ia);
            addrow(ib);
          }
          if (e < s1) addrow(s_src[e]);
        }
        if (cnt > 1) {
          float sc = 1.0f / (float)cnt;
#pragma unroll
          for (int q = 0; q < 8; ++q) aa[q] *= sc;
        }
      } else if (mid < nm) {
        addrow(uniq[mid]);
      }
      uint4 p;
      p.x = (unsigned int)f2bf(aa[0]) | ((unsigned int)f2bf(aa[1]) << 16);
      p.y = (unsigned int)f2bf(aa[2]) | ((unsigned int)f2bf(aa[3]) << 16);
      p.z = (unsigned int)f2bf(aa[4]) | ((unsigned int)f2bf(aa[5]) << 16);
      p.w = (unsigned int)f2bf(aa[6]) | ((unsigned int)f2bf(aa[7]) << 16);
      *(uint4*)&a_lds[(((er * 16 + seg) ^ (er & 7)) * 8)] = p;
    }
    __syncthreads();  // a_lds ready

    const unsigned short* wf = Wf + r * 16384;
#pragma unroll
    for (int kb = 0; kb < 4; ++kb) {
      int ku = kb * 4 + lg;
      bf16x8 af = *(const bf16x8*)&a_lds[((l15 * 16 + ku) ^ (l15 & 7)) * 8];
#pragma unroll
      for (int n = 0; n < 2; ++n) {
        int col = wc * 32 + n * 16 + l15;
        bf16x8 bfr = *(const bf16x8*)(wf + ((size_t)(ku * 128 + col)) * 8);
        acc[n] = __builtin_amdgcn_mfma_f32_16x16x32_bf16(af, bfr, acc[n], 0, 0, 0);
      }
    }
  }

  // epilogue: bias + relu, plain stores. C/D map: col=lane&15, row=(lane>>4)*4+reg
#pragma unroll
  for (int n = 0; n < 2; ++n) {
    int col = wc * 32 + n * 16 + l15;
    float bv = bvec[col];
#pragma unroll
    for (int q = 0; q < 4; ++q) {
      int row = mid0 + lg * 4 + q;
      float v = acc[n][q] + bv;
      Hacc[(size_t)row * 128 + col] = v > 0.f ? v : 0.f;
    }
  }
}

// ---------------- DistMult score: one wave per triple ----------------
__global__ void k_score(const float* __restrict__ H, const int* __restrict__ map,
                        const float* __restrict__ rel_emb, const int* __restrict__ tri_nodes,
                        const int* __restrict__ tri_rel, float* __restrict__ out, int B) {
  int w = (blockIdx.x * blockDim.x + threadIdx.x) >> 6;
  int lane = threadIdx.x & 63;
  if (w >= B) return;
  int s = map[tri_nodes[w * 2]];
  int o = map[tri_nodes[w * 2 + 1]];
  const float* hs = H + (size_t)s * 128;
  const float* ho = H + (size_t)o * 128;
  const float* rr = rel_emb + (size_t)tri_rel[w] * 128;
  float p = hs[lane] * ho[lane] * rr[lane] + hs[lane + 64] * ho[lane + 64] * rr[lane + 64];
#pragma unroll
  for (int ofs = 32; ofs > 0; ofs >>= 1) p += __shfl_down(p, ofs);
  if (lane == 0) out[w] = p;
}

extern "C" void kernel_launch(void* const* d_in, const int* in_sizes, int n_in,
                              void* d_out, int out_size, void* d_ws, size_t ws_size,
                              hipStream_t stream) {
  const float* X       = (const float*)d_in[0];
  const float* W_rel   = (const float*)d_in[1];
  const float* W_self  = (const float*)d_in[2];
  const float* bvec    = (const float*)d_in[3];
  const float* rel_emb = (const float*)d_in[4];
  const int* edge_src  = (const int*)d_in[5];
  const int* edge_dst  = (const int*)d_in[6];
  const int* edge_rel  = (const int*)d_in[7];
  const int* tri_nodes = (const int*)d_in[8];
  const int* tri_rel   = (const int*)d_in[9];

  int N  = in_sizes[0] / 128;   // 100000
  int E  = in_sizes[5];         // 1600000
  int nt = in_sizes[8];         // 2*B = 32768
  int B  = in_sizes[9];         // 16384
  int M  = nt * 8;              // 262144 combs
  int eblocks = (E + 255) / 256;
  int nwaves = eblocks * 4;

  char* ws = (char*)d_ws;
  int* map       = (int*)ws;                 // N
  int* counter   = map + N;                  // 1 (+pad 64)
  int* uniq      = counter + 64;             // nt
  int* cnt_c     = uniq + nt;                // M  (reused as Wf after scan_s3)
  int* seg_start = cnt_c + M;                // M+1 (+pad 64)
  int* seg_ofs   = seg_start + M + 64;       // M
  int* bsum      = seg_ofs + M;              // 256
  int* wcount    = bsum + 256;               // nwaves (+pad)
  int* s_src     = wcount + nwaves + 64;     // E
  float* Hacc    = (float*)(s_src + E);      // nt*128 floats
  unsigned short* Wf  = (unsigned short*)cnt_c;  // aliases dead cnt_c
  unsigned short* X16 = (unsigned short*)(Hacc + (size_t)nt * 128);  // N*128 bf16
  int2* c_pk = (int2*)(X16 + (size_t)N * 128);   // E int2 compacted pairs
  size_t need_big = ((char*)(c_pk + E)) - ws;    // ~65.5 MB; ws ~268 MB (r15 profile)
  bool bigws = ws_size >= need_big;

  hipMemsetAsync(map, 0xFF, (size_t)N * 4, stream);  // -1
  hipMemsetAsync(counter, 0, 64 * 4, stream);
  hipMemsetAsync(cnt_c, 0, (size_t)M * 4, stream);

  k_build_map<<<(nt + 255) / 256, 256, 0, stream>>>(tri_nodes, map, uniq, counter, nt);
  if (bigws) {
    k_count<<<eblocks, 256, 0, stream>>>(edge_src, edge_dst, edge_rel, map, cnt_c, E,
                                         X, X16, N * 16, c_pk, wcount);
  } else {
    k_count<<<eblocks, 256, 0, stream>>>(edge_src, edge_dst, edge_rel, map, cnt_c, E,
                                         X, (unsigned short*)Hacc /*unused*/, 0,
                                         (int2*)Hacc /*scratch, dead before k_fused*/,
                                         wcount);
  }
  k_scan_s1<<<256, 256, 0, stream>>>(cnt_c, bsum);
  k_scan_s2<<<1, 256, 0, stream>>>(bsum, seg_start, M);
  k_scan_s3<<<256, 256, 0, stream>>>(cnt_c, bsum, seg_start, seg_ofs);
  // cnt_c dead from here; overwrite with bf16 fragment-major weights
  k_cvt_w<<<(9 * 16384 + 255) / 256, 256, 0, stream>>>(W_rel, W_self, Wf);
  if (bigws) {
    k_scatter2<<<eblocks, 256, 0, stream>>>(c_pk, wcount, seg_ofs, s_src, nwaves);
    k_fused<1><<<nt / 16, 256, 0, stream>>>(X, X16, Wf, bvec, uniq, counter,
                                            seg_start, s_src, Hacc);
  } else {
    k_scatter<<<eblocks, 256, 0, stream>>>(edge_src, edge_dst, edge_rel, map, seg_ofs,
                                           s_src, E);
    k_fused<0><<<nt / 16, 256, 0, stream>>>(X, X16, Wf, bvec, uniq, counter,
                                            seg_start, s_src, Hacc);
  }
  k_score<<<(B * 64 + 255) / 256, 256, 0, stream>>>(Hacc, map, rel_emb, tri_nodes,
                                                    tri_rel, (float*)d_out, B);
}

// Round 18
// 119.842 us; speedup vs baseline: 1.2008x; 1.0697x over previous
//
#include <hip/hip_runtime.h>

typedef float f32x4 __attribute__((ext_vector_type(4)));
typedef short bf16x8 __attribute__((ext_vector_type(8)));

__device__ __forceinline__ unsigned short f2bf(float f) {
  unsigned int u = __float_as_uint(f);
  u += 0x7FFFu + ((u >> 16) & 1u);  // RNE
  return (unsigned short)(u >> 16);
}
__device__ __forceinline__ float bflo(unsigned int u) {  // low bf16 -> f32
  return __uint_as_float(u << 16);
}
__device__ __forceinline__ float bfhi(unsigned int u) {  // high bf16 -> f32
  return __uint_as_float(u & 0xFFFF0000u);
}

// ---------------- fused init: map=-1, counter=0, cnt_c=0 (replaces 3 memsets) ------
__global__ __launch_bounds__(256) void k_init(int4* __restrict__ map4, int n4,
                                              int* __restrict__ counter,
                                              int4* __restrict__ cnt4, int m4) {
  int i = blockIdx.x * 256 + threadIdx.x;  // 65536 threads
  int4 neg1 = make_int4(-1, -1, -1, -1);
  int4 zero = make_int4(0, 0, 0, 0);
  if (i < m4) cnt4[i] = zero;
  if (i < n4) map4[i] = neg1;
  if (i < 64) counter[i] = 0;
}

// ---------------- build node -> compact id map ----------------
__global__ void k_build_map(const int* __restrict__ tri_nodes, int* __restrict__ map,
                            int* __restrict__ uniq, int* __restrict__ counter, int n) {
  int i = blockIdx.x * blockDim.x + threadIdx.x;
  if (i >= n) return;
  int node = tri_nodes[i];
  int old = atomicCAS(&map[node], -1, -2);
  if (old == -1) {
    int mid = atomicAdd(counter, 1);
    uniq[mid] = node;
    map[node] = mid;
  }
}

// ------- ONE E-pass: count + fused X->bf16 + wave-compacted (comb,src) pairs -------
__global__ void k_count(const int* __restrict__ esrc, const int* __restrict__ edst,
                        const int* __restrict__ erel, const int* __restrict__ map,
                        int* __restrict__ cnt_c, int E,
                        const float* __restrict__ X, unsigned short* __restrict__ X16,
                        int total8, int2* __restrict__ c_pk, int* __restrict__ wcount) {
  int t = threadIdx.x;
  int i = blockIdx.x * 256 + t;
  if (i < total8) {  // fused cvt_x slice (independent streaming work)
    const float4* s = (const float4*)(X + (size_t)i * 8);
    float4 v0 = s[0], v1 = s[1];
    uint4 p;
    p.x = (unsigned int)f2bf(v0.x) | ((unsigned int)f2bf(v0.y) << 16);
    p.y = (unsigned int)f2bf(v0.z) | ((unsigned int)f2bf(v0.w) << 16);
    p.z = (unsigned int)f2bf(v1.x) | ((unsigned int)f2bf(v1.y) << 16);
    p.w = (unsigned int)f2bf(v1.z) | ((unsigned int)f2bf(v1.w) << 16);
    ((uint4*)X16)[i] = p;
  }
  bool valid = false;
  int comb = 0, src = 0;
  if (i < E) {
    int mid = map[edst[i]];
    if (mid >= 0) {
      valid = true;
      comb = mid * 8 + erel[i];
      src = esrc[i];
      atomicAdd(&cnt_c[comb], 1);  // 262K distinct addresses: low contention
    }
  }
  unsigned long long m = __ballot(valid);
  int lane = t & 63;
  int w = (blockIdx.x << 2) + (t >> 6);
  if (valid) {
    int rank = (int)__popcll(m & ((1ull << lane) - 1ull));
    c_pk[w * 64 + rank] = make_int2(comb, src);
  }
  if (lane == 0) wcount[w] = (int)__popcll(m);
}

// ---------------- scan stage 1: 256 blocks -> per-block sums ----------------
__global__ __launch_bounds__(256) void k_scan_s1(const int* __restrict__ cnt_c,
                                                 int* __restrict__ bsum) {
  __shared__ int sh[256];
  int tid = threadIdx.x;
  int base = blockIdx.x * 1024 + tid * 4;
  int s = cnt_c[base] + cnt_c[base + 1] + cnt_c[base + 2] + cnt_c[base + 3];
  sh[tid] = s;
  __syncthreads();
  for (int o = 1; o < 256; o <<= 1) {
    int x = (tid >= o) ? sh[tid - o] : 0;
    __syncthreads();
    sh[tid] += x;
    __syncthreads();
  }
  if (tid == 255) bsum[blockIdx.x] = sh[255];
}

// ------- scan stage 2+3 merged: each block derives its own global offset -------
__global__ __launch_bounds__(256) void k_scan_s3(const int* __restrict__ cnt_c,
                                                 const int* __restrict__ bsum,
                                                 int* __restrict__ seg_start,
                                                 int* __restrict__ seg_ofs, int M) {
  __shared__ int sh[256];
  int tid = threadIdx.x;
  // pass 1: scan the 256 block sums (1 KB) to get this block's exclusive offset
  int bv = bsum[tid];
  sh[tid] = bv;
  __syncthreads();
  for (int o = 1; o < 256; o <<= 1) {
    int x = (tid >= o) ? sh[tid - o] : 0;
    __syncthreads();
    sh[tid] += x;
    __syncthreads();
  }
  int incl_at_blk = sh[blockIdx.x];
  int total = sh[255];
  __syncthreads();
  int blk_off = incl_at_blk - bsum[blockIdx.x];  // exclusive prefix at blockIdx
  if (blockIdx.x == 0 && tid == 0) seg_start[M] = total;
  // pass 2: local scan over this block's 1024 cnt_c entries
  int base = blockIdx.x * 1024 + tid * 4;
  int c0 = cnt_c[base], c1 = cnt_c[base + 1], c2 = cnt_c[base + 2], c3 = cnt_c[base + 3];
  int s = c0 + c1 + c2 + c3;
  sh[tid] = s;
  __syncthreads();
  for (int o = 1; o < 256; o <<= 1) {
    int x = (tid >= o) ? sh[tid - o] : 0;
    __syncthreads();
    sh[tid] += x;
    __syncthreads();
  }
  int run = blk_off + sh[tid] - s;
  seg_start[base] = run; seg_ofs[base] = run; run += c0;
  seg_start[base + 1] = run; seg_ofs[base + 1] = run; run += c1;
  seg_start[base + 2] = run; seg_ofs[base + 2] = run; run += c2;
  seg_start[base + 3] = run; seg_ofs[base + 3] = run;
}

// ------- merged: W->bf16 fragment-major + scatter from wave-compacted pairs -------
// Wf slice: i < 147456 (aliases dead cnt_c). Scatter slice: wave-granular pairs.
__global__ void k_scw(const float* __restrict__ W_rel, const float* __restrict__ W_self,
                      unsigned short* __restrict__ Wf,
                      const int2* __restrict__ c_pk, const int* __restrict__ wcount,
                      int* __restrict__ seg_ofs, int* __restrict__ s_src, int nwaves) {
  int t = threadIdx.x;
  int i = blockIdx.x * 256 + t;
  if (i < 9 * 16384) {  // cvt_w slice
    int j = i & 7;
    int tmp = i >> 3;
    int col = tmp & 127;
    int ku = (tmp >> 7) & 15;
    int r = tmp >> 11;
    int d = ku * 8 + j;
    float v = (r < 8) ? W_rel[r * 16384 + d * 128 + col] : W_self[d * 128 + col];
    Wf[i] = f2bf(v);
  }
  int w = blockIdx.x * 4 + (t >> 6);
  if (w < nwaves) {
    int lane = t & 63;
    if (lane < wcount[w]) {
      int2 p = c_pk[w * 64 + lane];
      int pos = atomicAdd(&seg_ofs[p.x], 1);
      s_src[pos] = p.y;
    }
  }
}

// -------- fallback kernels (small-ws path only) --------
__global__ void k_cvt_w(const float* __restrict__ W_rel, const float* __restrict__ W_self,
                        unsigned short* __restrict__ Wf) {
  int i = blockIdx.x * 256 + threadIdx.x;
  if (i >= 9 * 16384) return;
  int j = i & 7;
  int tmp = i >> 3;
  int col = tmp & 127;
  int ku = (tmp >> 7) & 15;
  int r = tmp >> 11;
  int d = ku * 8 + j;
  float v = (r < 8) ? W_rel[r * 16384 + d * 128 + col] : W_self[d * 128 + col];
  Wf[i] = f2bf(v);
}
__global__ void k_scatter(const int* __restrict__ esrc, const int* __restrict__ edst,
                          const int* __restrict__ erel, const int* __restrict__ map,
                          int* __restrict__ seg_ofs, int* __restrict__ s_src, int E) {
  int i = blockIdx.x * blockDim.x + threadIdx.x;
  if (i >= E) return;
  int mid = map[edst[i]];
  if (mid >= 0) {
    int comb = mid * 8 + erel[i];
    int pos = atomicAdd(&seg_ofs[comb], 1);
    s_src[pos] = esrc[i];
  }
}

// ---------------- fused RGCN GEMM on matrix cores (r15/r17-proven, verbatim) -------
template <int XMODE>
__global__ __launch_bounds__(256) void k_fused(
    const float* __restrict__ X, const unsigned short* __restrict__ X16,
    const unsigned short* __restrict__ Wf, const float* __restrict__ bvec,
    const int* __restrict__ uniq, const int* __restrict__ counter,
    const int* __restrict__ seg_start, const int* __restrict__ s_src,
    float* __restrict__ Hacc) {
  __shared__ __align__(16) unsigned short a_lds[16 * 128];  // 4 KB, swizzled
  __shared__ int lds_src[768];                              // 3 KB index stage

  int nm = *counter;
  int mid0 = blockIdx.x * 16;
  if (mid0 >= nm) return;

  int t = threadIdx.x;
  int er = t >> 4, seg = t & 15;
  int lane = t & 63, l15 = lane & 15, lg = lane >> 4;
  int wc = t >> 6;
  int mid = mid0 + er;

  // stage this block's edge-index range (contiguous in comb-sorted order)
  int i0 = seg_start[mid0 * 8];
  int range = seg_start[mid0 * 8 + 128] - i0;
  for (int j = t; j < range && j < 768; j += 256) lds_src[j] = s_src[i0 + j];
  bool fits = (range <= 768);  // block-uniform

  f32x4 acc[2];
  {
    f32x4 z = {0.f, 0.f, 0.f, 0.f};
    acc[0] = z; acc[1] = z;
  }

  for (int r = 0; r < 9; ++r) {
    __syncthreads();  // orders staging (r=0) / prev MFMA before a_lds overwrite

    {  // stage A row er chunk seg (8 values)
      float aa[8];
#pragma unroll
      for (int q = 0; q < 8; ++q) aa[q] = 0.f;

      auto addrow = [&](int sidx) {
        if (XMODE == 0) {
          const float4* xr = (const float4*)(X + (size_t)sidx * 128) + seg * 2;
          float4 v0 = xr[0], v1 = xr[1];
          aa[0] += v0.x; aa[1] += v0.y; aa[2] += v0.z; aa[3] += v0.w;
          aa[4] += v1.x; aa[5] += v1.y; aa[6] += v1.z; aa[7] += v1.w;
        } else {
          uint4 u = *(const uint4*)(X16 + (size_t)sidx * 128 + seg * 8);
          aa[0] += bflo(u.x); aa[1] += bfhi(u.x);
          aa[2] += bflo(u.y); aa[3] += bfhi(u.y);
          aa[4] += bflo(u.z); aa[5] += bfhi(u.z);
          aa[6] += bflo(u.w); aa[7] += bfhi(u.w);
        }
      };

      if (r < 8) {
        int comb = mid * 8 + r;
        int s0 = seg_start[comb], s1 = seg_start[comb + 1];
        int cnt = s1 - s0;
        if (fits) {  // indices from LDS: chain = X16 load only
          int o = s0 - i0, oe = s1 - i0;
          for (; o + 2 <= oe; o += 2) {
            int ia = lds_src[o], ib = lds_src[o + 1];
            addrow(ia);
            addrow(ib);
          }
          if (o < oe) addrow(lds_src[o]);
        } else {     // rare fallback: original global path
          int e = s0;
          for (; e + 2 <= s1; e += 2) {
            int ia = s_src[e], ib = s_src[e + 1];
            addrow(ia);
            addrow(ib);
          }
          if (e < s1) addrow(s_src[e]);
        }
        if (cnt > 1) {
          float sc = 1.0f / (float)cnt;
#pragma unroll
          for (int q = 0; q < 8; ++q) aa[q] *= sc;
        }
      } else if (mid < nm) {
        addrow(uniq[mid]);
      }
      uint4 p;
      p.x = (unsigned int)f2bf(aa[0]) | ((unsigned int)f2bf(aa[1]) << 16);
      p.y = (unsigned int)f2bf(aa[2]) | ((unsigned int)f2bf(aa[3]) << 16);
      p.z = (unsigned int)f2bf(aa[4]) | ((unsigned int)f2bf(aa[5]) << 16);
      p.w = (unsigned int)f2bf(aa[6]) | ((unsigned int)f2bf(aa[7]) << 16);
      *(uint4*)&a_lds[(((er * 16 + seg) ^ (er & 7)) * 8)] = p;
    }
    __syncthreads();  // a_lds ready

    const unsigned short* wf = Wf + r * 16384;
#pragma unroll
    for (int kb = 0; kb < 4; ++kb) {
      int ku = kb * 4 + lg;
      bf16x8 af = *(const bf16x8*)&a_lds[((l15 * 16 + ku) ^ (l15 & 7)) * 8];
#pragma unroll
      for (int n = 0; n < 2; ++n) {
        int col = wc * 32 + n * 16 + l15;
        bf16x8 bfr = *(const bf16x8*)(wf + ((size_t)(ku * 128 + col)) * 8);
        acc[n] = __builtin_amdgcn_mfma_f32_16x16x32_bf16(af, bfr, acc[n], 0, 0, 0);
      }
    }
  }

  // epilogue: bias + relu, plain stores. C/D map: col=lane&15, row=(lane>>4)*4+reg
#pragma unroll
  for (int n = 0; n < 2; ++n) {
    int col = wc * 32 + n * 16 + l15;
    float bv = bvec[col];
#pragma unroll
    for (int q = 0; q < 4; ++q) {
      int row = mid0 + lg * 4 + q;
      float v = acc[n][q] + bv;
      Hacc[(size_t)row * 128 + col] = v > 0.f ? v : 0.f;
    }
  }
}

// ---------------- DistMult score: one wave per triple ----------------
__global__ void k_score(const float* __restrict__ H, const int* __restrict__ map,
                        const float* __restrict__ rel_emb, const int* __restrict__ tri_nodes,
                        const int* __restrict__ tri_rel, float* __restrict__ out, int B) {
  int w = (blockIdx.x * blockDim.x + threadIdx.x) >> 6;
  int lane = threadIdx.x & 63;
  if (w >= B) return;
  int s = map[tri_nodes[w * 2]];
  int o = map[tri_nodes[w * 2 + 1]];
  const float* hs = H + (size_t)s * 128;
  const float* ho = H + (size_t)o * 128;
  const float* rr = rel_emb + (size_t)tri_rel[w] * 128;
  float p = hs[lane] * ho[lane] * rr[lane] + hs[lane + 64] * ho[lane + 64] * rr[lane + 64];
#pragma unroll
  for (int ofs = 32; ofs > 0; ofs >>= 1) p += __shfl_down(p, ofs);
  if (lane == 0) out[w] = p;
}

extern "C" void kernel_launch(void* const* d_in, const int* in_sizes, int n_in,
                              void* d_out, int out_size, void* d_ws, size_t ws_size,
                              hipStream_t stream) {
  const float* X       = (const float*)d_in[0];
  const float* W_rel   = (const float*)d_in[1];
  const float* W_self  = (const float*)d_in[2];
  const float* bvec    = (const float*)d_in[3];
  const float* rel_emb = (const float*)d_in[4];
  const int* edge_src  = (const int*)d_in[5];
  const int* edge_dst  = (const int*)d_in[6];
  const int* edge_rel  = (const int*)d_in[7];
  const int* tri_nodes = (const int*)d_in[8];
  const int* tri_rel   = (const int*)d_in[9];

  int N  = in_sizes[0] / 128;   // 100000
  int E  = in_sizes[5];         // 1600000
  int nt = in_sizes[8];         // 2*B = 32768
  int B  = in_sizes[9];         // 16384
  int M  = nt * 8;              // 262144 combs
  int eblocks = (E + 255) / 256;
  int nwaves = eblocks * 4;

  char* ws = (char*)d_ws;
  int* map       = (int*)ws;                 // N
  int* counter   = map + N;                  // 1 (+pad 64)
  int* uniq      = counter + 64;             // nt
  int* cnt_c     = uniq + nt;                // M  (reused as Wf after scan_s3)
  int* seg_start = cnt_c + M;                // M+1 (+pad 64)
  int* seg_ofs   = seg_start + M + 64;       // M
  int* bsum      = seg_ofs + M;              // 256
  int* wcount    = bsum + 256;               // nwaves (+pad)
  int* s_src     = wcount + nwaves + 64;     // E
  float* Hacc    = (float*)(s_src + E);      // nt*128 floats
  unsigned short* Wf  = (unsigned short*)cnt_c;  // aliases dead cnt_c
  unsigned short* X16 = (unsigned short*)(Hacc + (size_t)nt * 128);  // N*128 bf16
  int2* c_pk = (int2*)(X16 + (size_t)N * 128);   // E int2 compacted pairs
  size_t need_big = ((char*)(c_pk + E)) - ws;    // ~65.5 MB; ws ~268 MB (r15 profile)
  bool bigws = ws_size >= need_big;

  // one init kernel replaces 3 memsets (map=-1, counter=0, cnt_c=0)
  k_init<<<256, 256, 0, stream>>>((int4*)map, N / 4, counter, (int4*)cnt_c, M / 4);
  k_build_map<<<(nt + 255) / 256, 256, 0, stream>>>(tri_nodes, map, uniq, counter, nt);
  if (bigws) {
    k_count<<<eblocks, 256, 0, stream>>>(edge_src, edge_dst, edge_rel, map, cnt_c, E,
                                         X, X16, N * 16, c_pk, wcount);
  } else {
    k_count<<<eblocks, 256, 0, stream>>>(edge_src, edge_dst, edge_rel, map, cnt_c, E,
                                         X, (unsigned short*)Hacc /*unused*/, 0,
                                         (int2*)Hacc /*scratch, dead before k_fused*/,
                                         wcount);
  }
  k_scan_s1<<<256, 256, 0, stream>>>(cnt_c, bsum);
  k_scan_s3<<<256, 256, 0, stream>>>(cnt_c, bsum, seg_start, seg_ofs, M);
  // cnt_c dead from here; k_scw overwrites it with Wf while scattering
  if (bigws) {
    k_scw<<<eblocks, 256, 0, stream>>>(W_rel, W_self, Wf, c_pk, wcount, seg_ofs,
                                       s_src, nwaves);
    k_fused<1><<<nt / 16, 256, 0, stream>>>(X, X16, Wf, bvec, uniq, counter,
                                            seg_start, s_src, Hacc);
  } else {
    k_cvt_w<<<(9 * 16384 + 255) / 256, 256, 0, stream>>>(W_rel, W_self, Wf);
    k_scatter<<<eblocks, 256, 0, stream>>>(edge_src, edge_dst, edge_rel, map, seg_ofs,
                                           s_src, E);
    k_fused<0><<<nt / 16, 256, 0, stream>>>(X, X16, Wf, bvec, uniq, counter,
                                            seg_start, s_src, Hacc);
  }
  k_score<<<(B * 64 + 255) / 256, 256, 0, stream>>>(Hacc, map, rel_emb, tri_nodes,
                                                    tri_rel, (float*)d_out, B);
}